// Round 1
// baseline (828.274 us; speedup 1.0000x reference)
//
#include <hip/hip_runtime.h>
#include <hip/hip_bf16.h>
#include <float.h>

#define NB 8
#define NC 256
#define HW 65536
#define KV 3
#define NF 128

// monotonic key: order-preserving float32 -> uint32 (larger float -> larger key)
__device__ __forceinline__ unsigned mono(float f) {
    unsigned u = __float_as_uint(f);
    return (u & 0x80000000u) ? ~u : (u | 0x80000000u);
}

// ---------------------------------------------------------------------------
// K1: per-pixel channel max. 1 thread = 4 pixels (float4), loop over 256 ch.
// Writes monotonic keys (B*HW u32) to ws.
// ---------------------------------------------------------------------------
__global__ __launch_bounds__(256) void chan_max_kernel(
    const float* __restrict__ x, unsigned* __restrict__ keys) {
    size_t t = (size_t)blockIdx.x * 256 + threadIdx.x;   // 0 .. 131071
    int b = (int)(t >> 14);          // 16384 float4-groups per batch
    int g = (int)(t & 16383);
    const float4* px = (const float4*)(x + (size_t)b * NC * HW) + g;
    float m0 = -FLT_MAX, m1 = -FLT_MAX, m2 = -FLT_MAX, m3 = -FLT_MAX;
#pragma unroll 8
    for (int c = 0; c < NC; ++c) {
        float4 v = px[(size_t)c * (HW / 4)];
        m0 = fmaxf(m0, v.x);
        m1 = fmaxf(m1, v.y);
        m2 = fmaxf(m2, v.z);
        m3 = fmaxf(m3, v.w);
    }
    uint4 kk;
    kk.x = mono(m0); kk.y = mono(m1); kk.z = mono(m2); kk.w = mono(m3);
    ((uint4*)keys)[t] = kk;
}

// ---------------------------------------------------------------------------
// K2: per-batch exact top-128 select over 65536 keys (radix-select, 4x8bit),
// stable tie-break (lowest pixel index first), rank-sorted descending.
// Writes sel[b][128] (pixel idx, desc order) and idxn_out (float).
// ---------------------------------------------------------------------------
__global__ __launch_bounds__(1024) void topk_select_kernel(
    const unsigned* __restrict__ keys, int* __restrict__ sel,
    float* __restrict__ out_idxn) {
    int b = blockIdx.x;
    const unsigned* kb = keys + (size_t)b * HW;
    int tid = threadIdx.x;   // 1024 threads

    __shared__ unsigned hist[256];
    __shared__ unsigned sh_thresh, sh_krem;
    __shared__ unsigned cand_key[256];
    __shared__ int cand_idx[256];
    __shared__ int eq_idx[512];
    __shared__ int n_gt, n_eq;

    if (tid == 0) { sh_thresh = 0u; sh_krem = NF; }

    for (int shift = 24; shift >= 0; shift -= 8) {
        if (tid < 256) hist[tid] = 0u;
        __syncthreads();
        unsigned thresh = sh_thresh;
        unsigned mask = (shift == 24) ? 0u : (0xFFFFFFFFu << (shift + 8));
        for (int i = tid; i < HW; i += 1024) {
            unsigned k = kb[i];
            if ((k & mask) == thresh)
                atomicAdd(&hist[(k >> shift) & 255], 1u);
        }
        __syncthreads();
        if (tid == 0) {
            unsigned krem = sh_krem;
            unsigned cum = 0;
            int bsel = 0;
            for (int bin = 255; bin >= 0; --bin) {
                if (cum + hist[bin] >= krem) { bsel = bin; break; }
                cum += hist[bin];
            }
            sh_thresh = thresh | ((unsigned)bsel << shift);
            sh_krem = krem - cum;
        }
        __syncthreads();
    }

    unsigned T = sh_thresh;
    int krem = (int)sh_krem;             // take krem lowest-index keys == T
    if (tid == 0) { n_gt = 0; n_eq = 0; }
    __syncthreads();

    for (int i = tid; i < HW; i += 1024) {
        unsigned k = kb[i];
        if (k > T) {
            int pos = atomicAdd(&n_gt, 1);
            if (pos < 256) { cand_key[pos] = k; cand_idx[pos] = i; }
        } else if (k == T) {
            int pos = atomicAdd(&n_eq, 1);
            if (pos < 512) eq_idx[pos] = i;
        }
    }
    __syncthreads();

    int ngt = n_gt;                       // == NF - krem by construction
    int neq = min(n_eq, 512);
    // pick krem lowest-index eq items; place at cand[ngt + rank]
    if (tid < neq) {
        int my = eq_idx[tid];
        int r = 0;
        for (int j = 0; j < neq; ++j)
            if (eq_idx[j] < my) r++;
        if (r < krem) { cand_key[ngt + r] = T; cand_idx[ngt + r] = my; }
    }
    __syncthreads();

    // rank-sort 128 items: key desc, index asc
    if (tid < NF) {
        unsigned mk = cand_key[tid];
        int mi = cand_idx[tid];
        int r = 0;
        for (int j = 0; j < NF; ++j) {
            unsigned k2 = cand_key[j];
            int i2 = cand_idx[j];
            if (k2 > mk || (k2 == mk && i2 < mi)) r++;
        }
        sel[b * NF + r] = mi;
        out_idxn[b * NF + r] = (float)mi;
    }
}

// ---------------------------------------------------------------------------
// K3: one wave per (b, n): re-read the 256 channels of selected pixel,
// top-3 (value desc, channel asc) via per-lane insert + shfl_xor butterfly.
// ---------------------------------------------------------------------------
__device__ __forceinline__ void ins3(float v, int c,
                                     float& v0, int& c0,
                                     float& v1, int& c1,
                                     float& v2, int& c2) {
    bool b0 = (v > v0) || (v == v0 && c < c0);
    bool b1 = (v > v1) || (v == v1 && c < c1);
    bool b2 = (v > v2) || (v == v2 && c < c2);
    if (b0) { v2 = v1; c2 = c1; v1 = v0; c1 = c0; v0 = v; c0 = c; }
    else if (b1) { v2 = v1; c2 = c1; v1 = v; c1 = c; }
    else if (b2) { v2 = v; c2 = c; }
}

__global__ __launch_bounds__(256) void gather_top3_kernel(
    const float* __restrict__ x, const int* __restrict__ sel,
    float* __restrict__ out_idxk, float* __restrict__ out_topk) {
    int gtid = blockIdx.x * 256 + threadIdx.x;
    int wid = gtid >> 6;                 // 0 .. 1023
    int lane = threadIdx.x & 63;
    int b = wid >> 7;
    int n = wid & 127;
    int p = sel[b * NF + n];

    const float* xb = x + (size_t)b * NC * HW + p;
    float v0 = -FLT_MAX, v1 = -FLT_MAX, v2 = -FLT_MAX;
    int c0 = 0x7FFFFFFF, c1 = 0x7FFFFFFF, c2 = 0x7FFFFFFF;
#pragma unroll
    for (int j = 0; j < 4; ++j) {
        int c = lane + j * 64;
        float v = xb[(size_t)c * HW];
        ins3(v, c, v0, c0, v1, c1, v2, c2);
    }
#pragma unroll
    for (int off = 1; off < 64; off <<= 1) {
        float w0 = __shfl_xor(v0, off);
        float w1 = __shfl_xor(v1, off);
        float w2 = __shfl_xor(v2, off);
        int d0 = __shfl_xor(c0, off);
        int d1 = __shfl_xor(c1, off);
        int d2 = __shfl_xor(c2, off);
        ins3(w0, d0, v0, c0, v1, c1, v2, c2);
        ins3(w1, d1, v0, c0, v1, c1, v2, c2);
        ins3(w2, d2, v0, c0, v1, c1, v2, c2);
    }
    if (lane == 0) {
        size_t base = (size_t)b * (KV * NF) + n;
        out_topk[base]            = v0;
        out_topk[base + NF]       = v1;
        out_topk[base + 2 * NF]   = v2;
        out_idxk[base]            = (float)c0;
        out_idxk[base + NF]       = (float)c1;
        out_idxk[base + 2 * NF]   = (float)c2;
    }
}

// ---------------------------------------------------------------------------
extern "C" void kernel_launch(void* const* d_in, const int* in_sizes, int n_in,
                              void* d_out, int out_size, void* d_ws, size_t ws_size,
                              hipStream_t stream) {
    const float* x = (const float*)d_in[0];
    float* out = (float*)d_out;
    // output layout: reduced_idxk (8*3*128) | reduced_topk (8*3*128) | idxn (8*1*128)
    float* out_idxk = out;
    float* out_topk = out + NB * KV * NF;
    float* out_idxn = out + 2 * NB * KV * NF;

    unsigned* keys = (unsigned*)d_ws;                          // 2 MB
    int* sel = (int*)((char*)d_ws + (size_t)NB * HW * 4);      // 4 KB

    chan_max_kernel<<<dim3(NB * HW / 4 / 256), dim3(256), 0, stream>>>(x, keys);
    topk_select_kernel<<<dim3(NB), dim3(1024), 0, stream>>>(keys, sel, out_idxn);
    gather_top3_kernel<<<dim3(NB * NF / 4), dim3(256), 0, stream>>>(x, sel, out_idxk, out_topk);
}

// Round 4
// 786.809 us; speedup vs baseline: 1.0527x; 1.0527x over previous
//
#include <hip/hip_runtime.h>
#include <hip/hip_bf16.h>
#include <float.h>

#define NB 8
#define NC 256
#define HW 65536
#define KV 3
#define NF 128

// monotonic key: order-preserving float32 -> uint32 (larger float -> larger key)
__device__ __forceinline__ unsigned mono(float f) {
    unsigned u = __float_as_uint(f);
    return (u & 0x80000000u) ? ~u : (u | 0x80000000u);
}
__device__ __forceinline__ float demono(unsigned k) {
    unsigned u = (k & 0x80000000u) ? (k ^ 0x80000000u) : ~k;
    return __uint_as_float(u);
}

// ---------------------------------------------------------------------------
// K1: fused per-pixel top-3 over 256 channels. 1 thread = 4 pixels (float4).
// Ascending-c insertion with strict > gives jax's stable (lowest-index) ties.
// Writes SoA planes: k0 (max key), k1, k2, packed channels. 8 MB total.
// ---------------------------------------------------------------------------
__global__ __launch_bounds__(256) void top3_kernel(
    const float* __restrict__ x,
    uint4* __restrict__ k0p, uint4* __restrict__ k1p,
    uint4* __restrict__ k2p, uint4* __restrict__ chp)
{
    unsigned t = blockIdx.x * 256 + threadIdx.x;   // 0 .. 131071
    int b = t >> 14;                               // 16384 float4-groups/batch
    int g = t & 16383;
    const float4* px = (const float4*)(x + (size_t)b * NC * HW) + g;

    float v0[4], v1[4], v2[4];
    int c0[4], c1[4], c2[4];
#pragma unroll
    for (int j = 0; j < 4; ++j) {
        v0[j] = v1[j] = v2[j] = -FLT_MAX;
        c0[j] = c1[j] = c2[j] = 0;
    }

#pragma unroll 4
    for (int c = 0; c < NC; ++c) {
        float4 val = px[(size_t)c * (HW / 4)];
        float vv[4] = {val.x, val.y, val.z, val.w};
#pragma unroll
        for (int j = 0; j < 4; ++j) {
            float v = vv[j];
            bool b0 = v > v0[j], b1 = v > v1[j], b2 = v > v2[j];
            float nv2 = b1 ? v1[j] : (b2 ? v : v2[j]);
            int   nc2 = b1 ? c1[j] : (b2 ? c : c2[j]);
            float nv1 = b0 ? v0[j] : (b1 ? v : v1[j]);
            int   nc1 = b0 ? c0[j] : (b1 ? c : c1[j]);
            float nv0 = b0 ? v : v0[j];
            int   nc0 = b0 ? c : c0[j];
            v2[j] = nv2; c2[j] = nc2;
            v1[j] = nv1; c1[j] = nc1;
            v0[j] = nv0; c0[j] = nc0;
        }
    }

    uint4 o0, o1, o2, oc;
    o0.x = mono(v0[0]); o0.y = mono(v0[1]); o0.z = mono(v0[2]); o0.w = mono(v0[3]);
    o1.x = mono(v1[0]); o1.y = mono(v1[1]); o1.z = mono(v1[2]); o1.w = mono(v1[3]);
    o2.x = mono(v2[0]); o2.y = mono(v2[1]); o2.z = mono(v2[2]); o2.w = mono(v2[3]);
    oc.x = (unsigned)c0[0] | ((unsigned)c1[0] << 8) | ((unsigned)c2[0] << 16);
    oc.y = (unsigned)c0[1] | ((unsigned)c1[1] << 8) | ((unsigned)c2[1] << 16);
    oc.z = (unsigned)c0[2] | ((unsigned)c1[2] << 8) | ((unsigned)c2[2] << 16);
    oc.w = (unsigned)c0[3] | ((unsigned)c1[3] << 8) | ((unsigned)c2[3] << 16);
    k0p[t] = o0; k1p[t] = o1; k2p[t] = o2; chp[t] = oc;
}

// ---------------------------------------------------------------------------
// K2: per-batch exact top-128 (radix select, 4x8bit) over the k0 plane,
// stable ties (lowest pixel idx), rank-sorted desc, then gathers k1/k2/chans
// and writes ALL outputs. Parallel suffix-scan; wave-aggregated histogram.
// ---------------------------------------------------------------------------
__global__ __launch_bounds__(1024) void select_kernel(
    const unsigned* __restrict__ k0p, const unsigned* __restrict__ k1p,
    const unsigned* __restrict__ k2p, const unsigned* __restrict__ chp,
    float* __restrict__ out_idxk, float* __restrict__ out_topk,
    float* __restrict__ out_idxn)
{
    int b = blockIdx.x;
    const unsigned* kb = k0p + (size_t)b * HW;
    int tid = threadIdx.x;                      // 1024 threads
    int lane = tid & 63;

    __shared__ unsigned hist[256];
    __shared__ unsigned suf[256];
    __shared__ unsigned sh_thresh, sh_krem;
    __shared__ unsigned cand_key[256];
    __shared__ int cand_idx[256];
    __shared__ int eq_idx[1024];
    __shared__ int n_gt, n_eq;

    if (tid == 0) { sh_thresh = 0u; sh_krem = NF; }

    for (int shift = 24; shift >= 0; shift -= 8) {
        if (tid < 256) hist[tid] = 0u;
        __syncthreads();
        unsigned thresh = sh_thresh;
        unsigned krem = sh_krem;
        unsigned mask = (shift == 24) ? 0u : (0xFFFFFFFFu << (shift + 8));
        // histogram (wave-aggregated fast path for clustered keys)
        for (int i = tid; i < HW; i += 1024) {
            unsigned k = kb[i];
            bool ok = ((k & mask) == thresh);
            unsigned bin = (k >> shift) & 255u;
            unsigned long long ball = __ballot(ok);
            unsigned fb = __shfl(bin, 0);
            bool uni = (ball == ~0ULL) && __all(bin == fb);
            if (uni) {
                if (lane == 0) atomicAdd(&hist[fb], 64u);
            } else if (ok) {
                atomicAdd(&hist[bin], 1u);
            }
        }
        __syncthreads();
        // parallel suffix scan: suf[i] = sum_{j>=i} hist[j]
        if (tid < 256) suf[tid] = hist[tid];
        __syncthreads();
        for (int off = 1; off < 256; off <<= 1) {
            unsigned add = 0;
            if (tid < 256 && tid + off < 256) add = suf[tid + off];
            __syncthreads();
            if (tid < 256) suf[tid] += add;
            __syncthreads();
        }
        // select boundary bin
        if (tid < 256) {
            unsigned cum = (tid == 255) ? 0u : suf[tid + 1];   // count > bin
            if (cum < krem && suf[tid] >= krem) {
                sh_thresh = thresh | ((unsigned)tid << shift);
                sh_krem = krem - cum;
            }
        }
        __syncthreads();
    }

    unsigned T = sh_thresh;
    int krem = (int)sh_krem;             // take krem lowest-index keys == T
    if (tid == 0) { n_gt = 0; n_eq = 0; }
    __syncthreads();

    for (int i = tid; i < HW; i += 1024) {
        unsigned k = kb[i];
        if (k > T) {
            int pos = atomicAdd(&n_gt, 1);
            if (pos < 256) { cand_key[pos] = k; cand_idx[pos] = i; }
        } else if (k == T) {
            int pos = atomicAdd(&n_eq, 1);
            if (pos < 1024) eq_idx[pos] = i;
        }
    }
    __syncthreads();

    int ngt = n_gt;                       // == NF - krem by construction
    int neq = min(n_eq, 1024);
    // pick krem lowest-index eq items; place at cand[ngt + rank]
    if (tid < neq) {
        int my = eq_idx[tid];
        int r = 0;
        for (int j = 0; j < neq; ++j)
            if (eq_idx[j] < my) r++;
        if (r < krem) { cand_key[ngt + r] = T; cand_idx[ngt + r] = my; }
    }
    __syncthreads();

    // rank-sort 128 items (key desc, index asc) + gather + write outputs
    if (tid < NF) {
        unsigned mk = cand_key[tid];
        int mi = cand_idx[tid];
        int r = 0;
        for (int j = 0; j < NF; ++j) {
            unsigned k2 = cand_key[j];
            int i2 = cand_idx[j];
            if (k2 > mk || (k2 == mk && i2 < mi)) r++;
        }
        size_t pix = (size_t)b * HW + mi;
        unsigned kk1 = k1p[pix];
        unsigned kk2 = k2p[pix];
        unsigned ch = chp[pix];
        out_idxn[b * NF + r] = (float)mi;
        size_t ob = (size_t)b * KV * NF + r;
        out_topk[ob]          = demono(mk);
        out_topk[ob + NF]     = demono(kk1);
        out_topk[ob + 2 * NF] = demono(kk2);
        out_idxk[ob]          = (float)(ch & 255u);
        out_idxk[ob + NF]     = (float)((ch >> 8) & 255u);
        out_idxk[ob + 2 * NF] = (float)((ch >> 16) & 255u);
    }
}

// ---------------------------------------------------------------------------
extern "C" void kernel_launch(void* const* d_in, const int* in_sizes, int n_in,
                              void* d_out, int out_size, void* d_ws, size_t ws_size,
                              hipStream_t stream) {
    const float* x = (const float*)d_in[0];
    float* out = (float*)d_out;
    // output layout: reduced_idxk (8*3*128) | reduced_topk (8*3*128) | idxn (8*1*128)
    float* out_idxk = out;
    float* out_topk = out + NB * KV * NF;
    float* out_idxn = out + 2 * NB * KV * NF;

    unsigned* k0p = (unsigned*)d_ws;               // 2 MB each plane
    unsigned* k1p = k0p + (size_t)NB * HW;
    unsigned* k2p = k1p + (size_t)NB * HW;
    unsigned* chp = k2p + (size_t)NB * HW;

    top3_kernel<<<dim3(NB * HW / 4 / 256), dim3(256), 0, stream>>>(
        x, (uint4*)k0p, (uint4*)k1p, (uint4*)k2p, (uint4*)chp);
    select_kernel<<<dim3(NB), dim3(1024), 0, stream>>>(
        k0p, k1p, k2p, chp, out_idxk, out_topk, out_idxn);
}

// Round 5
// 761.843 us; speedup vs baseline: 1.0872x; 1.0328x over previous
//
#include <hip/hip_runtime.h>
#include <hip/hip_bf16.h>
#include <float.h>

#define NB 8
#define NC 256
#define HW 65536
#define KV 3
#define NF 128

// monotonic key: order-preserving float32 -> uint32 (larger float -> larger key)
__device__ __forceinline__ unsigned mono(float f) {
    unsigned u = __float_as_uint(f);
    return (u & 0x80000000u) ? ~u : (u | 0x80000000u);
}

// ---------------------------------------------------------------------------
// K1: per-pixel channel max. 1 thread = 4 pixels (float4), loop over 256 ch.
// Minimal VALU (4 fmax/elem) so load issue runs at full rate. Writes the
// 2 MB monotonic-key plane only.
// ---------------------------------------------------------------------------
__global__ __launch_bounds__(256) void chan_max_kernel(
    const float* __restrict__ x, uint4* __restrict__ keys)
{
    unsigned t = blockIdx.x * 256 + threadIdx.x;   // 0 .. 131071
    int b = t >> 14;                               // 16384 float4-groups/batch
    int g = t & 16383;
    const float4* px = (const float4*)(x + (size_t)b * NC * HW) + g;
    float m0 = -FLT_MAX, m1 = -FLT_MAX, m2 = -FLT_MAX, m3 = -FLT_MAX;
#pragma unroll 16
    for (int c = 0; c < NC; ++c) {
        float4 v = px[(size_t)c * (HW / 4)];
        m0 = fmaxf(m0, v.x);
        m1 = fmaxf(m1, v.y);
        m2 = fmaxf(m2, v.z);
        m3 = fmaxf(m3, v.w);
    }
    uint4 kk;
    kk.x = mono(m0); kk.y = mono(m1); kk.z = mono(m2); kk.w = mono(m3);
    keys[t] = kk;
}

// ---------------------------------------------------------------------------
// K2: per-batch exact top-128 (radix select, 4x8bit) over the key plane,
// stable ties (lowest pixel idx), rank-sorted desc. uint4 loads everywhere.
// Writes sel[b][128] (pixel idx, rank order) and idxn_out (float).
// ---------------------------------------------------------------------------
__global__ __launch_bounds__(1024) void select_kernel(
    const unsigned* __restrict__ k0p, int* __restrict__ sel,
    float* __restrict__ out_idxn)
{
    int b = blockIdx.x;
    const uint4* kb4 = (const uint4*)(k0p + (size_t)b * HW);
    int tid = threadIdx.x;                      // 1024 threads
    int lane = tid & 63;

    __shared__ unsigned hist[256];
    __shared__ unsigned suf[256];
    __shared__ unsigned sh_thresh, sh_krem;
    __shared__ unsigned cand_key[256];
    __shared__ int cand_idx[256];
    __shared__ int eq_idx[1024];
    __shared__ int n_gt, n_eq;

    if (tid == 0) { sh_thresh = 0u; sh_krem = NF; }

    for (int shift = 24; shift >= 0; shift -= 8) {
        if (tid < 256) hist[tid] = 0u;
        __syncthreads();
        unsigned thresh = sh_thresh;
        unsigned krem = sh_krem;
        unsigned mask = (shift == 24) ? 0u : (0xFFFFFFFFu << (shift + 8));
        // histogram, uint4 per lane, wave-aggregated fast path
        for (int i = tid; i < HW / 4; i += 1024) {
            uint4 kk = kb4[i];
            unsigned ka[4] = {kk.x, kk.y, kk.z, kk.w};
            unsigned bn[4];
            bool ok[4];
            bool lane_uni = true;
#pragma unroll
            for (int j = 0; j < 4; ++j) {
                ok[j] = ((ka[j] & mask) == thresh);
                bn[j] = (ka[j] >> shift) & 255u;
                lane_uni = lane_uni && ok[j] && (bn[j] == bn[0]);
            }
            unsigned fb = __shfl(bn[0], 0);
            bool wave_uni = __all(lane_uni && bn[0] == fb);
            if (wave_uni) {
                if (lane == 0) atomicAdd(&hist[fb], 256u);
            } else {
#pragma unroll
                for (int j = 0; j < 4; ++j)
                    if (ok[j]) atomicAdd(&hist[bn[j]], 1u);
            }
        }
        __syncthreads();
        // parallel suffix scan: suf[i] = sum_{j>=i} hist[j]
        if (tid < 256) suf[tid] = hist[tid];
        __syncthreads();
        for (int off = 1; off < 256; off <<= 1) {
            unsigned add = 0;
            if (tid < 256 && tid + off < 256) add = suf[tid + off];
            __syncthreads();
            if (tid < 256) suf[tid] += add;
            __syncthreads();
        }
        // select boundary bin
        if (tid < 256) {
            unsigned cum = (tid == 255) ? 0u : suf[tid + 1];   // count > bin
            if (cum < krem && suf[tid] >= krem) {
                sh_thresh = thresh | ((unsigned)tid << shift);
                sh_krem = krem - cum;
            }
        }
        __syncthreads();
    }

    unsigned T = sh_thresh;
    int krem = (int)sh_krem;             // take krem lowest-index keys == T
    if (tid == 0) { n_gt = 0; n_eq = 0; }
    __syncthreads();

    for (int i = tid; i < HW / 4; i += 1024) {
        uint4 kk = kb4[i];
        unsigned ka[4] = {kk.x, kk.y, kk.z, kk.w};
#pragma unroll
        for (int j = 0; j < 4; ++j) {
            unsigned k = ka[j];
            int idx = 4 * i + j;
            if (k > T) {
                int pos = atomicAdd(&n_gt, 1);
                if (pos < 256) { cand_key[pos] = k; cand_idx[pos] = idx; }
            } else if (k == T) {
                int pos = atomicAdd(&n_eq, 1);
                if (pos < 1024) eq_idx[pos] = idx;
            }
        }
    }
    __syncthreads();

    int ngt = n_gt;                       // == NF - krem by construction
    int neq = min(n_eq, 1024);
    // pick krem lowest-index eq items; place at cand[ngt + rank]
    if (tid < neq) {
        int my = eq_idx[tid];
        int r = 0;
        for (int j = 0; j < neq; ++j)
            if (eq_idx[j] < my) r++;
        if (r < krem) { cand_key[ngt + r] = T; cand_idx[ngt + r] = my; }
    }
    __syncthreads();

    // rank-sort 128 items (key desc, index asc); write pixel list + idxn out
    if (tid < NF) {
        unsigned mk = cand_key[tid];
        int mi = cand_idx[tid];
        int r = 0;
        for (int j = 0; j < NF; ++j) {
            unsigned k2 = cand_key[j];
            int i2 = cand_idx[j];
            if (k2 > mk || (k2 == mk && i2 < mi)) r++;
        }
        sel[b * NF + r] = mi;
        out_idxn[b * NF + r] = (float)mi;
    }
}

// ---------------------------------------------------------------------------
// K3: one wave per (b, n): read the 256 channels of the selected pixel,
// top-3 (value desc, channel asc) via per-lane insert + shfl_xor butterfly.
// ---------------------------------------------------------------------------
__device__ __forceinline__ void ins3(float v, int c,
                                     float& v0, int& c0,
                                     float& v1, int& c1,
                                     float& v2, int& c2) {
    bool b0 = (v > v0) || (v == v0 && c < c0);
    bool b1 = (v > v1) || (v == v1 && c < c1);
    bool b2 = (v > v2) || (v == v2 && c < c2);
    if (b0) { v2 = v1; c2 = c1; v1 = v0; c1 = c0; v0 = v; c0 = c; }
    else if (b1) { v2 = v1; c2 = c1; v1 = v; c1 = c; }
    else if (b2) { v2 = v; c2 = c; }
}

__global__ __launch_bounds__(256) void gather_top3_kernel(
    const float* __restrict__ x, const int* __restrict__ sel,
    float* __restrict__ out_idxk, float* __restrict__ out_topk) {
    int gtid = blockIdx.x * 256 + threadIdx.x;
    int wid = gtid >> 6;                 // 0 .. 1023
    int lane = threadIdx.x & 63;
    int b = wid >> 7;
    int n = wid & 127;
    int p = sel[b * NF + n];

    const float* xb = x + (size_t)b * NC * HW + p;
    float v0 = -FLT_MAX, v1 = -FLT_MAX, v2 = -FLT_MAX;
    int c0 = 0x7FFFFFFF, c1 = 0x7FFFFFFF, c2 = 0x7FFFFFFF;
#pragma unroll
    for (int j = 0; j < 4; ++j) {
        int c = lane + j * 64;
        float v = xb[(size_t)c * HW];
        ins3(v, c, v0, c0, v1, c1, v2, c2);
    }
#pragma unroll
    for (int off = 1; off < 64; off <<= 1) {
        float w0 = __shfl_xor(v0, off);
        float w1 = __shfl_xor(v1, off);
        float w2 = __shfl_xor(v2, off);
        int d0 = __shfl_xor(c0, off);
        int d1 = __shfl_xor(c1, off);
        int d2 = __shfl_xor(c2, off);
        ins3(w0, d0, v0, c0, v1, c1, v2, c2);
        ins3(w1, d1, v0, c0, v1, c1, v2, c2);
        ins3(w2, d2, v0, c0, v1, c1, v2, c2);
    }
    if (lane == 0) {
        size_t base = (size_t)b * (KV * NF) + n;
        out_topk[base]            = v0;
        out_topk[base + NF]       = v1;
        out_topk[base + 2 * NF]   = v2;
        out_idxk[base]            = (float)c0;
        out_idxk[base + NF]       = (float)c1;
        out_idxk[base + 2 * NF]   = (float)c2;
    }
}

// ---------------------------------------------------------------------------
extern "C" void kernel_launch(void* const* d_in, const int* in_sizes, int n_in,
                              void* d_out, int out_size, void* d_ws, size_t ws_size,
                              hipStream_t stream) {
    const float* x = (const float*)d_in[0];
    float* out = (float*)d_out;
    // output layout: reduced_idxk (8*3*128) | reduced_topk (8*3*128) | idxn (8*1*128)
    float* out_idxk = out;
    float* out_topk = out + NB * KV * NF;
    float* out_idxn = out + 2 * NB * KV * NF;

    unsigned* k0p = (unsigned*)d_ws;                           // 2 MB key plane
    int* sel = (int*)((char*)d_ws + (size_t)NB * HW * 4);      // 4 KB

    chan_max_kernel<<<dim3(NB * HW / 4 / 256), dim3(256), 0, stream>>>(
        x, (uint4*)k0p);
    select_kernel<<<dim3(NB), dim3(1024), 0, stream>>>(k0p, sel, out_idxn);
    gather_top3_kernel<<<dim3(NB * NF / 4), dim3(256), 0, stream>>>(
        x, sel, out_idxk, out_topk);
}